// Round 1
// baseline (482.631 us; speedup 1.0000x reference)
//
#include <hip/hip_runtime.h>
#include <stdint.h>

// RNN: B=1024, T=200, D_in=300, D_h=256, D_out=2
// Phase 0 (prep): convert Wx (rows 0..299 of Wh, zero-pad to 320) and Whh
//   (rows 300..555) to bf16 MFMA-B-fragment order in ws.
// Phase 1: U[b,t,:] = x[b,t,:] @ Wx + bh  (bf16 MFMA, fp32 acc), stored bf16
//   in C-fragment order so phase 2 loads it as accumulator init directly.
// Phase 2: 64 blocks x 16 batch rows; 200 serial steps of
//   h = tanh(clip(U_t + h @ Whh)); Whh B-frags live in registers.
//   Epilogue: pre_out = clip(h @ Wo + bo), log_softmax, fp32 out.

typedef short s16x8 __attribute__((ext_vector_type(8)));
typedef float f32x4 __attribute__((ext_vector_type(4)));

__device__ __forceinline__ unsigned short f2bf(float f){
  uint32_t u = __builtin_bit_cast(uint32_t, f);
  u += 0x7fffu + ((u >> 16) & 1u);           // RNE
  return (unsigned short)(u >> 16);
}
__device__ __forceinline__ float bf2f(unsigned short s){
  uint32_t u = ((uint32_t)s) << 16;
  return __builtin_bit_cast(float, u);
}

// ---------------- prep: weight conversion to fragment order ----------------
// wxf layout:  [CT=0..15][ki=0..9][lane=0..63][j=0..7]  (K padded 300->320)
// whhf layout: [CT=0..15][ki=0..7][lane=0..63][j=0..7]
// value = W[k = ki*32 + (lane>>4)*8 + j][col = CT*16 + (lane&15)]
__global__ void prep_kernel(const float* __restrict__ Wh,
                            unsigned short* __restrict__ wxf,
                            unsigned short* __restrict__ whhf){
  int id = blockIdx.x * 256 + threadIdx.x;
  if (id < 81920){
    int j = id & 7, lane = (id >> 3) & 63, rem = id >> 9;
    int ki = rem % 10, CT = rem / 10;
    int k = ki * 32 + ((lane >> 4) << 3) + j;
    int col = CT * 16 + (lane & 15);
    wxf[id] = (k < 300) ? f2bf(Wh[k * 256 + col]) : (unsigned short)0;
  } else if (id < 81920 + 65536){
    int id2 = id - 81920;
    int j = id2 & 7, lane = (id2 >> 3) & 63, rem = id2 >> 9;
    int ki = rem & 7, CT = rem >> 3;
    int k = ki * 32 + ((lane >> 4) << 3) + j;
    int col = CT * 16 + (lane & 15);
    whhf[id2] = f2bf(Wh[(300 + k) * 256 + col]);
  }
}

// ---------------- phase 1: U = x @ Wx + bh ----------------
// grid: 12800 blocks = 64 batch-tiles x 200 timesteps; 512 threads (8 waves).
// wave w computes cols [w*32, w*32+32) of a 16-row tile.
__global__ __launch_bounds__(512) void phase1_kernel(
    const float* __restrict__ x, const float* __restrict__ bh,
    const unsigned short* __restrict__ wxf, unsigned short* __restrict__ U){
  int tile = blockIdx.x;
  int bt = tile / 200;
  int t  = tile - bt * 200;
  int tid = threadIdx.x;
  int w = tid >> 6, l = tid & 63;
  int m = l & 15, kg = l >> 4;
  const float* xp = x + (long)((bt * 16 + m) * 200 + t) * 300;
  int colA = w * 32 + m;
  float b0 = bh[colA], b1 = bh[colA + 16];
  f32x4 acc0 = {b0, b0, b0, b0};
  f32x4 acc1 = {b1, b1, b1, b1};
  const unsigned short* w0p = wxf + (w * 2 + 0) * 5120 + l * 8;
  const unsigned short* w1p = wxf + (w * 2 + 1) * 5120 + l * 8;
#pragma unroll
  for (int ki = 0; ki < 10; ki++){
    int k0 = ki * 32 + kg * 8;
    float v[8];
    if (k0 + 8 <= 300){
      float4 f0 = *(const float4*)(xp + k0);
      float4 f1 = *(const float4*)(xp + k0 + 4);
      v[0]=f0.x; v[1]=f0.y; v[2]=f0.z; v[3]=f0.w;
      v[4]=f1.x; v[5]=f1.y; v[6]=f1.z; v[7]=f1.w;
    } else {
#pragma unroll
      for (int j = 0; j < 8; j++) v[j] = (k0 + j < 300) ? xp[k0 + j] : 0.f;
    }
    s16x8 a;
#pragma unroll
    for (int j = 0; j < 8; j++) a[j] = (short)f2bf(v[j]);
    s16x8 bf0 = *(const s16x8*)(w0p + ki * 512);
    s16x8 bf1 = *(const s16x8*)(w1p + ki * 512);
    acc0 = __builtin_amdgcn_mfma_f32_16x16x32_bf16(a, bf0, acc0, 0, 0, 0);
    acc1 = __builtin_amdgcn_mfma_f32_16x16x32_bf16(a, bf1, acc1, 0, 0, 0);
  }
  s16x8 o;
#pragma unroll
  for (int r = 0; r < 4; r++){
    o[r]     = (short)f2bf(acc0[r]);
    o[4 + r] = (short)f2bf(acc1[r]);
  }
  *(s16x8*)(U + (long)tile * 4096 + (w * 64 + l) * 8) = o;
}

// ---------------- phase 2: serial recurrence ----------------
// grid: 64 blocks (16 batch rows each), 512 threads (8 waves).
__global__ __launch_bounds__(512) void phase2_kernel(
    const unsigned short* __restrict__ U, const unsigned short* __restrict__ whhf,
    const float* __restrict__ Wo, const float* __restrict__ bo,
    float* __restrict__ out){
  __shared__ unsigned short hlds[16 * 264];   // row stride 264 (2-way bank alias: free)
  __shared__ float flds[16][257];
  int bt = blockIdx.x;
  int tid = threadIdx.x;
  int w = tid >> 6, l = tid & 63;
  int m = l & 15, kg = l >> 4;

  // Whh B-fragments -> registers (64 VGPR/lane)
  s16x8 Bf0[8], Bf1[8];
#pragma unroll
  for (int ki = 0; ki < 8; ki++){
    Bf0[ki] = *(const s16x8*)(whhf + ((2 * w + 0) * 8 + ki) * 512 + l * 8);
    Bf1[ki] = *(const s16x8*)(whhf + ((2 * w + 1) * 8 + ki) * 512 + l * 8);
  }
  for (int i = tid; i < 16 * 264; i += 512) hlds[i] = 0;  // h0 = 0
  int ubase = bt * 819200 + (w * 64 + l) * 8;
  s16x8 u = *(const s16x8*)(U + ubase);  // U(t=0)
  __syncthreads();

  float hk[8];
  for (int t = 0; t < 200; t++){
    f32x4 acc0, acc1;
#pragma unroll
    for (int r = 0; r < 4; r++){
      acc0[r] = bf2f((unsigned short)u[r]);
      acc1[r] = bf2f((unsigned short)u[4 + r]);
    }
    int tn = (t < 199) ? t + 1 : 199;
    s16x8 un = *(const s16x8*)(U + bt * 819200 + tn * 4096 + (w * 64 + l) * 8);
    s16x8 a[8];
#pragma unroll
    for (int ki = 0; ki < 8; ki++)
      a[ki] = *(const s16x8*)(&hlds[m * 264 + ki * 32 + kg * 8]);
    __syncthreads();   // all reads of h(t-1) done before anyone writes h(t)
#pragma unroll
    for (int ki = 0; ki < 8; ki++){
      acc0 = __builtin_amdgcn_mfma_f32_16x16x32_bf16(a[ki], Bf0[ki], acc0, 0, 0, 0);
      acc1 = __builtin_amdgcn_mfma_f32_16x16x32_bf16(a[ki], Bf1[ki], acc1, 0, 0, 0);
    }
#pragma unroll
    for (int i = 0; i < 8; i++){
      float pre = (i < 4) ? acc0[i] : acc1[i - 4];
      float c = fminf(fmaxf(pre, -4.f), 4.f);
      float e = __expf(2.f * c);
      float h = 1.f - 2.f * __builtin_amdgcn_rcpf(e + 1.f);
      hk[i] = h;
      int r = i & 3, ct = i >> 2;
      hlds[(kg * 4 + r) * 264 + w * 32 + ct * 16 + m] = f2bf(h);
    }
    __syncthreads();
    u = un;
  }

  // -------- output head: pre_out = clip(h @ Wo + bo), log_softmax --------
#pragma unroll
  for (int i = 0; i < 8; i++){
    int r = i & 3, ct = i >> 2;
    flds[kg * 4 + r][w * 32 + ct * 16 + m] = hk[i];
  }
  __syncthreads();
  int rr = tid >> 5, q = tid & 31;
  float p0 = 0.f, p1 = 0.f;
#pragma unroll
  for (int j = 0; j < 8; j++){
    float hv = flds[rr][q + 32 * j];
    p0 += hv * Wo[(q + 32 * j) * 2 + 0];
    p1 += hv * Wo[(q + 32 * j) * 2 + 1];
  }
#pragma unroll
  for (int mm = 16; mm >= 1; mm >>= 1){
    p0 += __shfl_xor(p0, mm, 32);
    p1 += __shfl_xor(p1, mm, 32);
  }
  if (q == 0){
    p0 = fminf(fmaxf(p0 + bo[0], -4.f), 4.f);
    p1 = fminf(fmaxf(p1 + bo[1], -4.f), 4.f);
    float mx = fmaxf(p0, p1);
    float lse = mx + logf(__expf(p0 - mx) + __expf(p1 - mx));
    int orow = bt * 16 + rr;
    out[orow * 2 + 0] = p0 - lse;
    out[orow * 2 + 1] = p1 - lse;
  }
}

extern "C" void kernel_launch(void* const* d_in, const int* in_sizes, int n_in,
                              void* d_out, int out_size, void* d_ws, size_t ws_size,
                              hipStream_t stream){
  const float* x  = (const float*)d_in[0];
  const float* Wh = (const float*)d_in[1];
  const float* bh = (const float*)d_in[2];
  const float* Wo = (const float*)d_in[3];
  const float* bo = (const float*)d_in[4];
  float* out = (float*)d_out;

  // ws layout: U (bf16, 12800 tiles * 4096 elems = 104857600 B),
  //            wxf (163840 B), whhf (131072 B). Total ~105.2 MB.
  unsigned short* U    = (unsigned short*)d_ws;
  unsigned short* wxf  = (unsigned short*)((char*)d_ws + 104857600);
  unsigned short* whhf = (unsigned short*)((char*)d_ws + 104857600 + 163840);

  prep_kernel<<<576, 256, 0, stream>>>(Wh, wxf, whhf);
  phase1_kernel<<<12800, 512, 0, stream>>>(x, bh, wxf, U);
  phase2_kernel<<<64, 512, 0, stream>>>(U, whhf, Wo, bo, out);
}

// Round 2
// 240.626 us; speedup vs baseline: 2.0057x; 2.0057x over previous
//
#include <hip/hip_runtime.h>
#include <stdint.h>

// RNN: B=1024, T=200, D_in=300, D_h=256, D_out=2
// prep:   Wx / Whh -> bf16 MFMA-B-fragment order in ws.
// phase1: U[b,t,:] = x[b,t,:] @ Wx + bh. Block = 16 batch rows x 8 timesteps
//         (M=128) x 256 cols. x staged coalesced -> bf16 -> XOR-swizzled LDS
//         once; weights in registers; U stored in phase2 C-fragment layout
//         (coalesced 16B/lane stores).
// phase2: 64 blocks x 16 batch rows; 200 serial steps of
//         h = tanh(clip(U_t + h @ Whh)); Whh frags in registers; h double-
//         buffered in LDS -> ONE barrier per step. Head + log_softmax fused.

typedef short s16x8 __attribute__((ext_vector_type(8)));
typedef float f32x4 __attribute__((ext_vector_type(4)));

__device__ __forceinline__ unsigned short f2bf(float f){
  uint32_t u = __builtin_bit_cast(uint32_t, f);
  u += 0x7fffu + ((u >> 16) & 1u);           // RNE
  return (unsigned short)(u >> 16);
}
__device__ __forceinline__ float bf2f(unsigned short s){
  uint32_t u = ((uint32_t)s) << 16;
  return __builtin_bit_cast(float, u);
}
__device__ __forceinline__ uint32_t pack2(float a, float b){
  return (uint32_t)f2bf(a) | ((uint32_t)f2bf(b) << 16);
}

// ---------------- prep: weight conversion to fragment order ----------------
// wxf layout:  [CT=0..15][ki=0..9][lane=0..63][j=0..7]  (K padded 300->320)
// whhf layout: [CT=0..15][ki=0..7][lane=0..63][j=0..7]
// value = W[k = ki*32 + (lane>>4)*8 + j][col = CT*16 + (lane&15)]
__global__ void prep_kernel(const float* __restrict__ Wh,
                            unsigned short* __restrict__ wxf,
                            unsigned short* __restrict__ whhf){
  int id = blockIdx.x * 256 + threadIdx.x;
  if (id < 81920){
    int j = id & 7, lane = (id >> 3) & 63, rem = id >> 9;
    int ki = rem % 10, CT = rem / 10;
    int k = ki * 32 + ((lane >> 4) << 3) + j;
    int col = CT * 16 + (lane & 15);
    wxf[id] = (k < 300) ? f2bf(Wh[k * 256 + col]) : (unsigned short)0;
  } else if (id < 81920 + 65536){
    int id2 = id - 81920;
    int j = id2 & 7, lane = (id2 >> 3) & 63, rem = id2 >> 9;
    int ki = rem & 7, CT = rem >> 3;
    int k = ki * 32 + ((lane >> 4) << 3) + j;
    int col = CT * 16 + (lane & 15);
    whhf[id2] = f2bf(Wh[(300 + k) * 256 + col]);
  }
}

// ---------------- phase 1: U = x @ Wx + bh ----------------
// grid: 1600 blocks = 64 batch-tiles x 25 t-groups; 512 threads (8 waves).
// LDS x-tile: rows = tt*16 + bl (128 rows), 320 bf16/row, XOR swizzle
// idx ^= ((row&7)<<3) in ushort units (both write and read sides).
__global__ __launch_bounds__(512, 4) void phase1_kernel(
    const float* __restrict__ x, const float* __restrict__ bh,
    const unsigned short* __restrict__ wxf, unsigned short* __restrict__ U){
  __shared__ unsigned short hx[128 * 320];   // 80 KB -> 2 blocks/CU
  int blk = blockIdx.x;
  int bt = blk / 25;
  int t0 = (blk - bt * 25) * 8;
  int tid = threadIdx.x;
  int w = tid >> 6, l = tid & 63;
  int m = l & 15, kg = l >> 4;

  // ---- stage 16 chunks of 2400 contiguous floats -> bf16 LDS ----
  const float4* xb = (const float4*)x + (long)(bt * 16) * 15000 + t0 * 75;
  for (int i = tid; i < 9600; i += 512){
    int bl = i / 600;
    int j  = i - bl * 600;
    float4 v = xb[(long)bl * 15000 + j];
    int tt = j / 75;
    int k4 = j - tt * 75;
    int idx = (((tt * 16 + bl) * 320) + k4 * 4) ^ ((bl & 7) << 3);
    *(uint2*)(&hx[idx]) = make_uint2(pack2(v.x, v.y), pack2(v.z, v.w));
  }
  // zero-pad k = 300..319 (128 rows x 20 elems)
  for (int i = tid; i < 640; i += 512){
    int r = i / 5, q = i - r * 5;
    int idx = (r * 320 + 300 + q * 4) ^ ((r & 7) << 3);
    *(uint2*)(&hx[idx]) = make_uint2(0u, 0u);
  }

  // ---- weights -> registers (2 col-tiles per wave) ----
  s16x8 Bf0[10], Bf1[10];
  const unsigned short* w0p = wxf + (2 * w + 0) * 5120 + l * 8;
  const unsigned short* w1p = wxf + (2 * w + 1) * 5120 + l * 8;
#pragma unroll
  for (int ki = 0; ki < 10; ki++){
    Bf0[ki] = *(const s16x8*)(w0p + ki * 512);
    Bf1[ki] = *(const s16x8*)(w1p + ki * 512);
  }
  float b0 = bh[w * 32 + m], b1 = bh[w * 32 + 16 + m];
  __syncthreads();

  unsigned short* ub = U + (long)bt * 819200 + (long)t0 * 4096 + (w * 64 + l) * 8;
  int abase = m * 320 + kg * 8;
  int swz = (m & 7) << 3;
#pragma unroll 1
  for (int tt = 0; tt < 8; tt++){
    f32x4 acc0 = {b0, b0, b0, b0};
    f32x4 acc1 = {b1, b1, b1, b1};
    int ab = tt * 5120 + abase;
#pragma unroll
    for (int ki = 0; ki < 10; ki++){
      s16x8 a = *(const s16x8*)(&hx[(ab + ki * 32) ^ swz]);
      acc0 = __builtin_amdgcn_mfma_f32_16x16x32_bf16(a, Bf0[ki], acc0, 0, 0, 0);
      acc1 = __builtin_amdgcn_mfma_f32_16x16x32_bf16(a, Bf1[ki], acc1, 0, 0, 0);
    }
    s16x8 o;
#pragma unroll
    for (int r = 0; r < 4; r++){
      o[r]     = (short)f2bf(acc0[r]);
      o[4 + r] = (short)f2bf(acc1[r]);
    }
    *(s16x8*)(ub + tt * 4096) = o;  // coalesced 1KB/wave
  }
}

// ---------------- phase 2: serial recurrence ----------------
// grid: 64 blocks (16 batch rows each), 512 threads (8 waves).
// h double-buffered in LDS -> exactly one __syncthreads per step.
__global__ __launch_bounds__(512) void phase2_kernel(
    const unsigned short* __restrict__ U, const unsigned short* __restrict__ whhf,
    const float* __restrict__ Wo, const float* __restrict__ bo,
    float* __restrict__ out){
  __shared__ unsigned short h2[2][16 * 264];  // stride 264: 2-way alias, free
  __shared__ float flds[16][257];
  int bt = blockIdx.x;
  int tid = threadIdx.x;
  int w = tid >> 6, l = tid & 63;
  int m = l & 15, kg = l >> 4;

  // Whh B-fragments -> registers (64 VGPR/lane)
  s16x8 Bf0[8], Bf1[8];
#pragma unroll
  for (int ki = 0; ki < 8; ki++){
    Bf0[ki] = *(const s16x8*)(whhf + ((2 * w + 0) * 8 + ki) * 512 + l * 8);
    Bf1[ki] = *(const s16x8*)(whhf + ((2 * w + 1) * 8 + ki) * 512 + l * 8);
  }
  for (int i = tid; i < 16 * 264; i += 512) h2[0][i] = 0;  // h0 = 0
  const unsigned short* ubase = U + (long)bt * 819200 + (w * 64 + l) * 8;
  s16x8 u = *(const s16x8*)ubase;  // U(t=0)
  __syncthreads();

  float hk[8];
  int p = 0;
  for (int t = 0; t < 200; t++){
    f32x4 acc0, acc1;
    f32x4 acc0b = {0.f, 0.f, 0.f, 0.f}, acc1b = {0.f, 0.f, 0.f, 0.f};
#pragma unroll
    for (int r = 0; r < 4; r++){
      acc0[r] = bf2f((unsigned short)u[r]);
      acc1[r] = bf2f((unsigned short)u[4 + r]);
    }
    int tn = (t < 199) ? t + 1 : 199;
    s16x8 un = *(const s16x8*)(ubase + (long)tn * 4096);
    s16x8 a[8];
#pragma unroll
    for (int ki = 0; ki < 8; ki++)
      a[ki] = *(const s16x8*)(&h2[p][m * 264 + ki * 32 + kg * 8]);
    // split chains: depth 4 instead of 8
#pragma unroll
    for (int ki = 0; ki < 4; ki++){
      acc0  = __builtin_amdgcn_mfma_f32_16x16x32_bf16(a[ki],     Bf0[ki],     acc0,  0, 0, 0);
      acc1  = __builtin_amdgcn_mfma_f32_16x16x32_bf16(a[ki],     Bf1[ki],     acc1,  0, 0, 0);
      acc0b = __builtin_amdgcn_mfma_f32_16x16x32_bf16(a[ki + 4], Bf0[ki + 4], acc0b, 0, 0, 0);
      acc1b = __builtin_amdgcn_mfma_f32_16x16x32_bf16(a[ki + 4], Bf1[ki + 4], acc1b, 0, 0, 0);
    }
#pragma unroll
    for (int i = 0; i < 8; i++){
      float pre = (i < 4) ? (acc0[i] + acc0b[i]) : (acc1[i - 4] + acc1b[i - 4]);
      float c = fminf(fmaxf(pre, -4.f), 4.f);
      float e = __expf(2.f * c);
      float h = 1.f - 2.f * __builtin_amdgcn_rcpf(e + 1.f);
      hk[i] = h;
      int r = i & 3, ct = i >> 2;
      h2[p ^ 1][(kg * 4 + r) * 264 + w * 32 + ct * 16 + m] = f2bf(h);
    }
    __syncthreads();   // h(t) fully written; next step reads p^1
    p ^= 1;
    u = un;
  }

  // -------- output head: pre_out = clip(h @ Wo + bo), log_softmax --------
#pragma unroll
  for (int i = 0; i < 8; i++){
    int r = i & 3, ct = i >> 2;
    flds[kg * 4 + r][w * 32 + ct * 16 + m] = hk[i];
  }
  __syncthreads();
  int rr = tid >> 5, q = tid & 31;
  float p0 = 0.f, p1 = 0.f;
#pragma unroll
  for (int j = 0; j < 8; j++){
    float hv = flds[rr][q + 32 * j];
    p0 += hv * Wo[(q + 32 * j) * 2 + 0];
    p1 += hv * Wo[(q + 32 * j) * 2 + 1];
  }
#pragma unroll
  for (int mm = 16; mm >= 1; mm >>= 1){
    p0 += __shfl_xor(p0, mm, 32);
    p1 += __shfl_xor(p1, mm, 32);
  }
  if (q == 0){
    p0 = fminf(fmaxf(p0 + bo[0], -4.f), 4.f);
    p1 = fminf(fmaxf(p1 + bo[1], -4.f), 4.f);
    float mx = fmaxf(p0, p1);
    float lse = mx + logf(__expf(p0 - mx) + __expf(p1 - mx));
    int orow = bt * 16 + rr;
    out[orow * 2 + 0] = p0 - lse;
    out[orow * 2 + 1] = p1 - lse;
  }
}

extern "C" void kernel_launch(void* const* d_in, const int* in_sizes, int n_in,
                              void* d_out, int out_size, void* d_ws, size_t ws_size,
                              hipStream_t stream){
  const float* x  = (const float*)d_in[0];
  const float* Wh = (const float*)d_in[1];
  const float* bh = (const float*)d_in[2];
  const float* Wo = (const float*)d_in[3];
  const float* bo = (const float*)d_in[4];
  float* out = (float*)d_out;

  unsigned short* U    = (unsigned short*)d_ws;                               // 104857600 B
  unsigned short* wxf  = (unsigned short*)((char*)d_ws + 104857600);          // 163840 B
  unsigned short* whhf = (unsigned short*)((char*)d_ws + 104857600 + 163840); // 131072 B

  prep_kernel<<<576, 256, 0, stream>>>(Wh, wxf, whhf);
  phase1_kernel<<<1600, 512, 0, stream>>>(x, bh, wxf, U);
  phase2_kernel<<<64, 512, 0, stream>>>(U, whhf, Wo, bo, out);
}